// Round 1
// baseline (233.151 us; speedup 1.0000x reference)
//
#include <hip/hip_runtime.h>
#include <math.h>

#define RAD2DEG 57.29577951308232f

constexpr int S1_BLOCKS = 2048;
constexpr int S1_TPB    = 256;

__device__ __forceinline__ float wrapdeg(float e) {
    e = fabsf(e);
    return e > 180.0f ? 360.0f - e : e;
}

__device__ __forceinline__ void per_row(
    float l1x, float l2x, float l1y, float l2y, float l1z, float l2z,
    float e1x, float e1y, float e1z, float e2x, float e2y, float e2z,
    int mw,
    float& sS, float& sM, float& sC0, float& sM1, float& sM2)
{
    float dx, dy, dz;
    dx = e1x - l1x; dy = e1y - l1y; dz = e1z - l1z;
    float d11 = dx*dx + dy*dy + dz*dz;
    dx = e2x - l2x; dy = e2y - l2y; dz = e2z - l2z;
    float d22 = dx*dx + dy*dy + dz*dz;
    dx = e2x - l1x; dy = e2y - l1y; dz = e2z - l1z;
    float d21 = dx*dx + dy*dy + dz*dz;
    dx = e1x - l2x; dy = e1y - l2y; dz = e1z - l2z;
    float d12 = dx*dx + dy*dy + dz*dz;

    sS += d11;  // global single-loss sum of squares (all rows)

    float mixed = fminf(d11 + d22, d21 + d12) * (1.0f / 3.0f);
    if (mw != 0) sM += mixed; else sC0 += 1.0f;

    float la1 = atan2f(l1y, l1x) * RAD2DEG;
    float la2 = atan2f(l2y, l2x) * RAD2DEG;
    float ea1 = atan2f(e1y, e1x) * RAD2DEG;
    float ea2 = atan2f(e2y, e2x) * RAD2DEG;

    float e11 = wrapdeg(la1 - ea1);
    float e22 = wrapdeg(la2 - ea2);
    float e12 = wrapdeg(la1 - ea2);
    float e21 = wrapdeg(la2 - ea1);

    bool ud = (e11 + e22) < (e12 + e21);
    sM1 += ud ? e11 : e12;
    sM2 += ud ? e22 : e21;
}

__global__ __launch_bounds__(S1_TPB) void stage1_kernel(
    const float* __restrict__ label,
    const float* __restrict__ est,
    const int*   __restrict__ mix,
    float* __restrict__ partials,   // [gridDim.x][5]
    int P)                          // number of row-pairs = B/2
{
    const int tid = threadIdx.x;
    const int gid = blockIdx.x * S1_TPB + tid;
    const int T   = gridDim.x * S1_TPB;

    float sS = 0.f, sM = 0.f, sC0 = 0.f, sM1 = 0.f, sM2 = 0.f;

    for (int p = gid; p < P; p += T) {
        const float4* lab4 = (const float4*)(label + (size_t)p * 12);
        const float4* est4 = (const float4*)(est   + (size_t)p * 12);
        float4 L0 = lab4[0], L1 = lab4[1], L2 = lab4[2];
        float4 E0 = est4[0], E1 = est4[1], E2 = est4[2];
        int2 mw = ((const int2*)mix)[p];

        // even row of the pair: label[6b..6b+5], est[6b..6b+5]
        per_row(L0.x, L0.y, L0.z, L0.w, L1.x, L1.y,
                E0.x, E0.y, E0.z, E0.w, E1.x, E1.y,
                mw.x, sS, sM, sC0, sM1, sM2);
        // odd row
        per_row(L1.z, L1.w, L2.x, L2.y, L2.z, L2.w,
                E1.z, E1.w, E2.x, E2.y, E2.z, E2.w,
                mw.y, sS, sM, sC0, sM1, sM2);
    }

    // wave (64-lane) shuffle reduction
    for (int off = 32; off > 0; off >>= 1) {
        sS  += __shfl_down(sS,  off, 64);
        sM  += __shfl_down(sM,  off, 64);
        sC0 += __shfl_down(sC0, off, 64);
        sM1 += __shfl_down(sM1, off, 64);
        sM2 += __shfl_down(sM2, off, 64);
    }

    __shared__ float red[S1_TPB / 64][5];
    const int wid = tid >> 6, lane = tid & 63;
    if (lane == 0) {
        red[wid][0] = sS; red[wid][1] = sM; red[wid][2] = sC0;
        red[wid][3] = sM1; red[wid][4] = sM2;
    }
    __syncthreads();
    if (tid == 0) {
        float r0 = 0.f, r1 = 0.f, r2 = 0.f, r3 = 0.f, r4 = 0.f;
        #pragma unroll
        for (int w = 0; w < S1_TPB / 64; ++w) {
            r0 += red[w][0]; r1 += red[w][1]; r2 += red[w][2];
            r3 += red[w][3]; r4 += red[w][4];
        }
        float* out = partials + (size_t)blockIdx.x * 5;
        out[0] = r0; out[1] = r1; out[2] = r2; out[3] = r3; out[4] = r4;
    }
}

__global__ __launch_bounds__(256) void stage2_kernel(
    const float* __restrict__ partials,
    float* __restrict__ out,
    int nblocks,
    long long Btot)
{
    const int tid = threadIdx.x;
    double aS = 0, aM = 0, aC0 = 0, aM1 = 0, aM2 = 0;
    for (int r = tid; r < nblocks; r += 256) {
        const float* row = partials + (size_t)r * 5;
        aS += row[0]; aM += row[1]; aC0 += row[2]; aM1 += row[3]; aM2 += row[4];
    }
    for (int off = 32; off > 0; off >>= 1) {
        aS  += __shfl_down(aS,  off, 64);
        aM  += __shfl_down(aM,  off, 64);
        aC0 += __shfl_down(aC0, off, 64);
        aM1 += __shfl_down(aM1, off, 64);
        aM2 += __shfl_down(aM2, off, 64);
    }
    __shared__ double red[4][5];
    const int wid = tid >> 6, lane = tid & 63;
    if (lane == 0) {
        red[wid][0] = aS; red[wid][1] = aM; red[wid][2] = aC0;
        red[wid][3] = aM1; red[wid][4] = aM2;
    }
    __syncthreads();
    if (tid == 0) {
        double S = 0, M = 0, C0 = 0, M1 = 0, M2 = 0;
        #pragma unroll
        for (int w = 0; w < 4; ++w) {
            S += red[w][0]; M += red[w][1]; C0 += red[w][2];
            M1 += red[w][3]; M2 += red[w][4];
        }
        const double Bd = (double)Btot;
        const double single_loss = S / (3.0 * Bd);
        out[0] = (float)((C0 * single_loss + M) / Bd);
        out[1] = (float)(M1 / Bd);
        out[2] = (float)(M2 / Bd);
    }
}

extern "C" void kernel_launch(void* const* d_in, const int* in_sizes, int n_in,
                              void* d_out, int out_size, void* d_ws, size_t ws_size,
                              hipStream_t stream) {
    const float* label = (const float*)d_in[0];   // (B,3,2) f32
    const float* est   = (const float*)d_in[1];   // (B,6)   f32
    const int*   mix   = (const int*)d_in[2];     // (B,)    i32
    float* out = (float*)d_out;
    float* partials = (float*)d_ws;

    const long long B = (long long)in_sizes[2];
    const int P = (int)(B / 2);  // B = 4194304, even

    stage1_kernel<<<S1_BLOCKS, S1_TPB, 0, stream>>>(label, est, mix, partials, P);
    stage2_kernel<<<1, 256, 0, stream>>>(partials, out, S1_BLOCKS, B);
}

// Round 2
// 231.409 us; speedup vs baseline: 1.0075x; 1.0075x over previous
//
#include <hip/hip_runtime.h>
#include <math.h>

#define RAD2DEG 57.29577951308232f

constexpr int S1_BLOCKS = 2048;
constexpr int S1_TPB    = 256;

// Absolute angular distance in degrees between vectors (ax,ay) and (bx,by).
// == wrap(atan2(ay,ax)*RAD2DEG - atan2(by,bx)*RAD2DEG) from the reference.
// Branchless: atan2(|cross|, dot) in [0, pi] via octant-reduced minimax poly.
__device__ __forceinline__ float angdist_deg(float ax, float ay,
                                             float bx, float by) {
    float dot = ax * bx + ay * by;
    float cr  = fabsf(ay * bx - ax * by);
    float ad  = fabsf(dot);
    float mn  = fminf(cr, ad);
    float mx  = fmaxf(cr, ad);
    // mx==0 only if one vector is exactly (0,0); guard to avoid 0*inf=NaN.
    float t   = mn * __builtin_amdgcn_rcpf(fmaxf(mx, 1e-37f));
    float s   = t * t;
    // minimax poly for atan(t), t in [0,1]; max err ~2.3e-5 rad (~0.0013 deg)
    float p = fmaf(s, -0.01172120f, 0.05265332f);
    p = fmaf(s, p, -0.11643287f);
    p = fmaf(s, p,  0.19354346f);
    p = fmaf(s, p, -0.33262347f);
    p = fmaf(s, p,  0.99997726f);
    float a = t * p;                                   // [0, pi/4]
    a = (cr > ad)    ? (1.57079632679489662f - a) : a; // [0, pi/2]
    a = (dot < 0.0f) ? (3.14159265358979323f - a) : a; // [0, pi]
    return a * RAD2DEG;
}

__device__ __forceinline__ void per_row(
    float l1x, float l2x, float l1y, float l2y, float l1z, float l2z,
    float e1x, float e1y, float e1z, float e2x, float e2y, float e2z,
    int mw,
    float& sS, float& sM, float& sC0, float& sM1, float& sM2)
{
    float dx, dy, dz;
    dx = e1x - l1x; dy = e1y - l1y; dz = e1z - l1z;
    float d11 = dx*dx + dy*dy + dz*dz;
    dx = e2x - l2x; dy = e2y - l2y; dz = e2z - l2z;
    float d22 = dx*dx + dy*dy + dz*dz;
    dx = e2x - l1x; dy = e2y - l1y; dz = e2z - l1z;
    float d21 = dx*dx + dy*dy + dz*dz;
    dx = e1x - l2x; dy = e1y - l2y; dz = e1z - l2z;
    float d12 = dx*dx + dy*dy + dz*dz;

    sS += d11;  // global single-loss sum of squares (all rows)

    float mixed = fminf(d11 + d22, d21 + d12) * (1.0f / 3.0f);
    float m = (mw != 0) ? 1.0f : 0.0f;
    sM  += m * mixed;
    sC0 += 1.0f - m;

    // angular distances label-vs-est (deg, in [0,180])
    float e11 = angdist_deg(l1x, l1y, e1x, e1y);
    float e22 = angdist_deg(l2x, l2y, e2x, e2y);
    float e12 = angdist_deg(l1x, l1y, e2x, e2y);
    float e21 = angdist_deg(l2x, l2y, e1x, e1y);

    bool ud = (e11 + e22) < (e12 + e21);
    sM1 += ud ? e11 : e12;
    sM2 += ud ? e22 : e21;
}

__global__ __launch_bounds__(S1_TPB) void stage1_kernel(
    const float* __restrict__ label,
    const float* __restrict__ est,
    const int*   __restrict__ mix,
    float* __restrict__ partials,   // [gridDim.x][5]
    int P)                          // number of row-pairs = B/2
{
    const int tid = threadIdx.x;
    const int gid = blockIdx.x * S1_TPB + tid;
    const int T   = gridDim.x * S1_TPB;

    float sS = 0.f, sM = 0.f, sC0 = 0.f, sM1 = 0.f, sM2 = 0.f;

    for (int p = gid; p < P; p += T) {
        const float4* lab4 = (const float4*)(label + (size_t)p * 12);
        const float4* est4 = (const float4*)(est   + (size_t)p * 12);
        float4 L0 = lab4[0], L1 = lab4[1], L2 = lab4[2];
        float4 E0 = est4[0], E1 = est4[1], E2 = est4[2];
        int2 mw = ((const int2*)mix)[p];

        // even row of the pair
        per_row(L0.x, L0.y, L0.z, L0.w, L1.x, L1.y,
                E0.x, E0.y, E0.z, E0.w, E1.x, E1.y,
                mw.x, sS, sM, sC0, sM1, sM2);
        // odd row
        per_row(L1.z, L1.w, L2.x, L2.y, L2.z, L2.w,
                E1.z, E1.w, E2.x, E2.y, E2.z, E2.w,
                mw.y, sS, sM, sC0, sM1, sM2);
    }

    // wave (64-lane) shuffle reduction
    for (int off = 32; off > 0; off >>= 1) {
        sS  += __shfl_down(sS,  off, 64);
        sM  += __shfl_down(sM,  off, 64);
        sC0 += __shfl_down(sC0, off, 64);
        sM1 += __shfl_down(sM1, off, 64);
        sM2 += __shfl_down(sM2, off, 64);
    }

    __shared__ float red[S1_TPB / 64][5];
    const int wid = tid >> 6, lane = tid & 63;
    if (lane == 0) {
        red[wid][0] = sS; red[wid][1] = sM; red[wid][2] = sC0;
        red[wid][3] = sM1; red[wid][4] = sM2;
    }
    __syncthreads();
    if (tid == 0) {
        float r0 = 0.f, r1 = 0.f, r2 = 0.f, r3 = 0.f, r4 = 0.f;
        #pragma unroll
        for (int w = 0; w < S1_TPB / 64; ++w) {
            r0 += red[w][0]; r1 += red[w][1]; r2 += red[w][2];
            r3 += red[w][3]; r4 += red[w][4];
        }
        float* out = partials + (size_t)blockIdx.x * 5;
        out[0] = r0; out[1] = r1; out[2] = r2; out[3] = r3; out[4] = r4;
    }
}

__global__ __launch_bounds__(256) void stage2_kernel(
    const float* __restrict__ partials,
    float* __restrict__ out,
    int nblocks,
    long long Btot)
{
    const int tid = threadIdx.x;
    double aS = 0, aM = 0, aC0 = 0, aM1 = 0, aM2 = 0;
    for (int r = tid; r < nblocks; r += 256) {
        const float* row = partials + (size_t)r * 5;
        aS += row[0]; aM += row[1]; aC0 += row[2]; aM1 += row[3]; aM2 += row[4];
    }
    for (int off = 32; off > 0; off >>= 1) {
        aS  += __shfl_down(aS,  off, 64);
        aM  += __shfl_down(aM,  off, 64);
        aC0 += __shfl_down(aC0, off, 64);
        aM1 += __shfl_down(aM1, off, 64);
        aM2 += __shfl_down(aM2, off, 64);
    }
    __shared__ double red[4][5];
    const int wid = tid >> 6, lane = tid & 63;
    if (lane == 0) {
        red[wid][0] = aS; red[wid][1] = aM; red[wid][2] = aC0;
        red[wid][3] = aM1; red[wid][4] = aM2;
    }
    __syncthreads();
    if (tid == 0) {
        double S = 0, M = 0, C0 = 0, M1 = 0, M2 = 0;
        #pragma unroll
        for (int w = 0; w < 4; ++w) {
            S += red[w][0]; M += red[w][1]; C0 += red[w][2];
            M1 += red[w][3]; M2 += red[w][4];
        }
        const double Bd = (double)Btot;
        const double single_loss = S / (3.0 * Bd);
        out[0] = (float)((C0 * single_loss + M) / Bd);
        out[1] = (float)(M1 / Bd);
        out[2] = (float)(M2 / Bd);
    }
}

extern "C" void kernel_launch(void* const* d_in, const int* in_sizes, int n_in,
                              void* d_out, int out_size, void* d_ws, size_t ws_size,
                              hipStream_t stream) {
    const float* label = (const float*)d_in[0];   // (B,3,2) f32
    const float* est   = (const float*)d_in[1];   // (B,6)   f32
    const int*   mix   = (const int*)d_in[2];     // (B,)    i32
    float* out = (float*)d_out;
    float* partials = (float*)d_ws;

    const long long B = (long long)in_sizes[2];
    const int P = (int)(B / 2);  // B = 4194304, even

    stage1_kernel<<<S1_BLOCKS, S1_TPB, 0, stream>>>(label, est, mix, partials, P);
    stage2_kernel<<<1, 256, 0, stream>>>(partials, out, S1_BLOCKS, B);
}

// Round 3
// 229.662 us; speedup vs baseline: 1.0152x; 1.0076x over previous
//
#include <hip/hip_runtime.h>
#include <math.h>

#define RAD2DEG 57.29577951308232f

constexpr int S1_BLOCKS = 2048;
constexpr int S1_TPB    = 256;
constexpr int CHUNK     = 256;          // pairs per block-iteration
constexpr int CH_F      = CHUNK * 12;   // floats per array per chunk (3072)
constexpr int CH_V4     = CHUNK * 3;    // float4s per array per chunk (768)

typedef __attribute__((address_space(1))) const unsigned int gu32;
typedef __attribute__((address_space(3))) unsigned int       lu32;

// async 16B/lane global->LDS DMA; lds base must be wave-uniform (HW writes
// base + lane*16). Completion tracked by vmcnt; __syncthreads() drains it.
__device__ __forceinline__ void g2lds16(const float4* g, float* lds) {
    __builtin_amdgcn_global_load_lds((gu32*)g, (lu32*)lds, 16, 0, 0);
}

// Absolute angular distance in degrees between vectors (ax,ay) and (bx,by).
// == wrap(atan2(ay,ax)*RAD2DEG - atan2(by,bx)*RAD2DEG) from the reference.
__device__ __forceinline__ float angdist_deg(float ax, float ay,
                                             float bx, float by) {
    float dot = ax * bx + ay * by;
    float cr  = fabsf(ay * bx - ax * by);
    float ad  = fabsf(dot);
    float mn  = fminf(cr, ad);
    float mx  = fmaxf(cr, ad);
    float t   = mn * __builtin_amdgcn_rcpf(fmaxf(mx, 1e-37f));
    float s   = t * t;
    // minimax poly for atan(t), t in [0,1]; max err ~2.3e-5 rad (~0.0013 deg)
    float p = fmaf(s, -0.01172120f, 0.05265332f);
    p = fmaf(s, p, -0.11643287f);
    p = fmaf(s, p,  0.19354346f);
    p = fmaf(s, p, -0.33262347f);
    p = fmaf(s, p,  0.99997726f);
    float a = t * p;                                   // [0, pi/4]
    a = (cr > ad)    ? (1.57079632679489662f - a) : a; // [0, pi/2]
    a = (dot < 0.0f) ? (3.14159265358979323f - a) : a; // [0, pi]
    return a * RAD2DEG;
}

__device__ __forceinline__ void per_row(
    float l1x, float l2x, float l1y, float l2y, float l1z, float l2z,
    float e1x, float e1y, float e1z, float e2x, float e2y, float e2z,
    int mw,
    float& sS, float& sM, float& sC0, float& sM1, float& sM2)
{
    float dx, dy, dz;
    dx = e1x - l1x; dy = e1y - l1y; dz = e1z - l1z;
    float d11 = dx*dx + dy*dy + dz*dz;
    dx = e2x - l2x; dy = e2y - l2y; dz = e2z - l2z;
    float d22 = dx*dx + dy*dy + dz*dz;
    dx = e2x - l1x; dy = e2y - l1y; dz = e2z - l1z;
    float d21 = dx*dx + dy*dy + dz*dz;
    dx = e1x - l2x; dy = e1y - l2y; dz = e1z - l2z;
    float d12 = dx*dx + dy*dy + dz*dz;

    sS += d11;

    float mixed = fminf(d11 + d22, d21 + d12) * (1.0f / 3.0f);
    float m = (mw != 0) ? 1.0f : 0.0f;
    sM  += m * mixed;
    sC0 += 1.0f - m;

    float e11 = angdist_deg(l1x, l1y, e1x, e1y);
    float e22 = angdist_deg(l2x, l2y, e2x, e2y);
    float e12 = angdist_deg(l1x, l1y, e2x, e2y);
    float e21 = angdist_deg(l2x, l2y, e1x, e1y);

    bool ud = (e11 + e22) < (e12 + e21);
    sM1 += ud ? e11 : e12;
    sM2 += ud ? e22 : e21;
}

__global__ __launch_bounds__(S1_TPB) void stage1_kernel(
    const float* __restrict__ label,
    const float* __restrict__ est,
    const int*   __restrict__ mix,
    float* __restrict__ partials,   // [gridDim.x][5]
    int P)                          // number of row-pairs = B/2
{
    __shared__ float labS[CH_F];
    __shared__ float estS[CH_F];

    const int tid  = threadIdx.x;
    const int wid  = tid >> 6;
    const int lane = tid & 63;

    const float4* lab4 = (const float4*)label;
    const float4* est4 = (const float4*)est;
    const int2*   mix2 = (const int2*)mix;

    float sS = 0.f, sM = 0.f, sC0 = 0.f, sM1 = 0.f, sM2 = 0.f;

    const int nchunks = P / CHUNK;
    for (int c = blockIdx.x; c < nchunks; c += gridDim.x) {
        const int vbase = c * CH_V4;   // float4 index of chunk start
        #pragma unroll
        for (int j = 0; j < 3; ++j) {
            const int vi = j * 256 + wid * 64;       // wave-uniform within chunk
            g2lds16(lab4 + vbase + vi + lane, labS + vi * 4);
            g2lds16(est4 + vbase + vi + lane, estS + vi * 4);
        }
        int2 mw = mix2[c * CHUNK + tid];             // coalesced, direct
        __syncthreads();

        const float4* Lv = (const float4*)(labS + tid * 12);
        const float4* Ev = (const float4*)(estS + tid * 12);
        float4 L0 = Lv[0], L1 = Lv[1], L2 = Lv[2];
        float4 E0 = Ev[0], E1 = Ev[1], E2 = Ev[2];

        per_row(L0.x, L0.y, L0.z, L0.w, L1.x, L1.y,
                E0.x, E0.y, E0.z, E0.w, E1.x, E1.y,
                mw.x, sS, sM, sC0, sM1, sM2);
        per_row(L1.z, L1.w, L2.x, L2.y, L2.z, L2.w,
                E1.z, E1.w, E2.x, E2.y, E2.z, E2.w,
                mw.y, sS, sM, sC0, sM1, sM2);
        __syncthreads();   // protect LDS before next chunk's DMA
    }

    // tail pairs (P % CHUNK != 0), strided direct path
    for (int p = nchunks * CHUNK + blockIdx.x * S1_TPB + tid; p < P;
         p += gridDim.x * S1_TPB) {
        const float4* lv = (const float4*)(label + (size_t)p * 12);
        const float4* ev = (const float4*)(est   + (size_t)p * 12);
        float4 L0 = lv[0], L1 = lv[1], L2 = lv[2];
        float4 E0 = ev[0], E1 = ev[1], E2 = ev[2];
        int2 mw = mix2[p];
        per_row(L0.x, L0.y, L0.z, L0.w, L1.x, L1.y,
                E0.x, E0.y, E0.z, E0.w, E1.x, E1.y,
                mw.x, sS, sM, sC0, sM1, sM2);
        per_row(L1.z, L1.w, L2.x, L2.y, L2.z, L2.w,
                E1.z, E1.w, E2.x, E2.y, E2.z, E2.w,
                mw.y, sS, sM, sC0, sM1, sM2);
    }

    // wave (64-lane) shuffle reduction
    for (int off = 32; off > 0; off >>= 1) {
        sS  += __shfl_down(sS,  off, 64);
        sM  += __shfl_down(sM,  off, 64);
        sC0 += __shfl_down(sC0, off, 64);
        sM1 += __shfl_down(sM1, off, 64);
        sM2 += __shfl_down(sM2, off, 64);
    }

    __shared__ float red[S1_TPB / 64][5];
    if (lane == 0) {
        red[wid][0] = sS; red[wid][1] = sM; red[wid][2] = sC0;
        red[wid][3] = sM1; red[wid][4] = sM2;
    }
    __syncthreads();
    if (tid == 0) {
        float r0 = 0.f, r1 = 0.f, r2 = 0.f, r3 = 0.f, r4 = 0.f;
        #pragma unroll
        for (int w = 0; w < S1_TPB / 64; ++w) {
            r0 += red[w][0]; r1 += red[w][1]; r2 += red[w][2];
            r3 += red[w][3]; r4 += red[w][4];
        }
        float* out = partials + (size_t)blockIdx.x * 5;
        out[0] = r0; out[1] = r1; out[2] = r2; out[3] = r3; out[4] = r4;
    }
}

__global__ __launch_bounds__(256) void stage2_kernel(
    const float* __restrict__ partials,
    float* __restrict__ out,
    int nblocks,
    long long Btot)
{
    const int tid = threadIdx.x;
    double aS = 0, aM = 0, aC0 = 0, aM1 = 0, aM2 = 0;
    for (int r = tid; r < nblocks; r += 256) {
        const float* row = partials + (size_t)r * 5;
        aS += row[0]; aM += row[1]; aC0 += row[2]; aM1 += row[3]; aM2 += row[4];
    }
    for (int off = 32; off > 0; off >>= 1) {
        aS  += __shfl_down(aS,  off, 64);
        aM  += __shfl_down(aM,  off, 64);
        aC0 += __shfl_down(aC0, off, 64);
        aM1 += __shfl_down(aM1, off, 64);
        aM2 += __shfl_down(aM2, off, 64);
    }
    __shared__ double red[4][5];
    const int wid = tid >> 6, lane = tid & 63;
    if (lane == 0) {
        red[wid][0] = aS; red[wid][1] = aM; red[wid][2] = aC0;
        red[wid][3] = aM1; red[wid][4] = aM2;
    }
    __syncthreads();
    if (tid == 0) {
        double S = 0, M = 0, C0 = 0, M1 = 0, M2 = 0;
        #pragma unroll
        for (int w = 0; w < 4; ++w) {
            S += red[w][0]; M += red[w][1]; C0 += red[w][2];
            M1 += red[w][3]; M2 += red[w][4];
        }
        const double Bd = (double)Btot;
        const double single_loss = S / (3.0 * Bd);
        out[0] = (float)((C0 * single_loss + M) / Bd);
        out[1] = (float)(M1 / Bd);
        out[2] = (float)(M2 / Bd);
    }
}

extern "C" void kernel_launch(void* const* d_in, const int* in_sizes, int n_in,
                              void* d_out, int out_size, void* d_ws, size_t ws_size,
                              hipStream_t stream) {
    const float* label = (const float*)d_in[0];   // (B,3,2) f32
    const float* est   = (const float*)d_in[1];   // (B,6)   f32
    const int*   mix   = (const int*)d_in[2];     // (B,)    i32
    float* out = (float*)d_out;
    float* partials = (float*)d_ws;

    const long long B = (long long)in_sizes[2];
    const int P = (int)(B / 2);  // B = 4194304, even

    stage1_kernel<<<S1_BLOCKS, S1_TPB, 0, stream>>>(label, est, mix, partials, P);
    stage2_kernel<<<1, 256, 0, stream>>>(partials, out, S1_BLOCKS, B);
}